// Round 4
// baseline (125.209 us; speedup 1.0000x reference)
//
#include <hip/hip_runtime.h>
#include <hip/hip_bf16.h>
#include <hip/hip_cooperative_groups.h>
#include <math.h>

namespace cg = cooperative_groups;

// Problem: image_feats (128,64,128) fp32 -> F0: 128 x 8192
//          lang_feats  (128,32,128) fp32 -> F1: 128 x 4096
//          out (128,) fp32 = column sums over i of exp(A_g)*(A_g - A_f)
//
// Single cooperative kernel:
//   phase 1: split-K Gram via MFMA 32x32x16 bf16 hi/lo splitting (4 products),
//            fragments straight from global (no LDS); partials + diag to ws.
//   grid sync
//   phase 2 (blocks 0..127): split-K reduce (8-acc ILP), log-softmax both
//            sets concurrently (block halves), KL, atomic column-sum.
// Diagonal dist forced to 0 (matches reference construction f[i]-f[i]).

#define NROW 128
#define PAIRS 16384
#define D0 8192
#define D1 4096
#define CK 64
#define NC0 128          // D0/CK
#define NC1 64           // D1/CK
#define NCHUNK 192

typedef short v8s  __attribute__((ext_vector_type(8)));
typedef float v16f __attribute__((ext_vector_type(16)));

union Frag {
    v8s s;
    __hip_bfloat162 h[4];
};

__device__ __forceinline__ void splitPair(float a, float b, Frag& hi, Frag& lo, int idx) {
    __hip_bfloat162 h = __float22bfloat162_rn(make_float2(a, b));
    const float ra = a - __bfloat162float(h.x);
    const float rb = b - __bfloat162float(h.y);
    __hip_bfloat162 l = __float22bfloat162_rn(make_float2(ra, rb));
    hi.h[idx] = h;
    lo.h[idx] = l;
}

__device__ __forceinline__ void loadFrag(const float* __restrict__ p, Frag& hi, Frag& lo) {
    const float4 v0 = *(const float4*)(p);
    const float4 v1 = *(const float4*)(p + 4);
    splitPair(v0.x, v0.y, hi, lo, 0);
    splitPair(v0.z, v0.w, hi, lo, 1);
    splitPair(v1.x, v1.y, hi, lo, 2);
    splitPair(v1.z, v1.w, hi, lo, 3);
}

__device__ __forceinline__ float waveMax64(float v) {
#pragma unroll
    for (int off = 32; off > 0; off >>= 1) v = fmaxf(v, __shfl_xor(v, off, 64));
    return v;
}
__device__ __forceinline__ float waveSum64(float v) {
#pragma unroll
    for (int off = 32; off > 0; off >>= 1) v += __shfl_xor(v, off, 64);
    return v;
}

__global__ __launch_bounds__(256) void k_fused(
    const float* __restrict__ F0, const float* __restrict__ F1,
    float* __restrict__ partials, float* __restrict__ diagP,
    const float* __restrict__ temp, float* __restrict__ out)
{
    const int b = blockIdx.x;
    const int t = threadIdx.x;
    if (b == 0 && t < NROW) out[t] = 0.0f;   // zero for phase-2 atomics

    // ================= phase 1: Gram partials for chunk b =================
    {
        const float* F; int D, k0;
        if (b < NC0) { F = F0; D = D0; k0 = b * CK; }
        else         { F = F1; D = D1; k0 = (b - NC0) * CK; }

        const int wave  = t >> 6;
        const int wy    = wave >> 1;
        const int wx    = wave & 1;
        const int lane  = t & 63;
        const int r32   = lane & 31;
        const int khalf = lane >> 5;

        const int rA0 = wy * 64 + r32;
        const int rA1 = wy * 64 + 32 + r32;
        const int rB0 = wx * 64 + r32;
        const int rB1 = wx * 64 + 32 + r32;

        v16f acc[2][2];
#pragma unroll
        for (int ti = 0; ti < 2; ++ti)
#pragma unroll
            for (int tj = 0; tj < 2; ++tj)
#pragma unroll
                for (int r = 0; r < 16; ++r) acc[ti][tj][r] = 0.0f;

#pragma unroll
        for (int g = 0; g < CK / 16; ++g) {
            const int col = k0 + g * 16 + khalf * 8;
            Frag Ah[2], Al[2], Bh[2], Bl[2];
            loadFrag(F + (size_t)rA0 * D + col, Ah[0], Al[0]);
            loadFrag(F + (size_t)rA1 * D + col, Ah[1], Al[1]);
            loadFrag(F + (size_t)rB0 * D + col, Bh[0], Bl[0]);
            loadFrag(F + (size_t)rB1 * D + col, Bh[1], Bl[1]);
#pragma unroll
            for (int ti = 0; ti < 2; ++ti)
#pragma unroll
                for (int tj = 0; tj < 2; ++tj) {
                    acc[ti][tj] = __builtin_amdgcn_mfma_f32_32x32x16_bf16(
                        Ah[ti].s, Bh[tj].s, acc[ti][tj], 0, 0, 0);
                    acc[ti][tj] = __builtin_amdgcn_mfma_f32_32x32x16_bf16(
                        Ah[ti].s, Bl[tj].s, acc[ti][tj], 0, 0, 0);
                    acc[ti][tj] = __builtin_amdgcn_mfma_f32_32x32x16_bf16(
                        Al[ti].s, Bh[tj].s, acc[ti][tj], 0, 0, 0);
                    acc[ti][tj] = __builtin_amdgcn_mfma_f32_32x32x16_bf16(
                        Al[ti].s, Bl[tj].s, acc[ti][tj], 0, 0, 0);
                }
        }

        // C/D layout (m74/m101): col = lane&31, row = (reg&3)+8*(reg>>2)+4*(lane>>5)
        float* __restrict__ pout = partials + (size_t)b * PAIRS;
#pragma unroll
        for (int ti = 0; ti < 2; ++ti)
#pragma unroll
            for (int tj = 0; tj < 2; ++tj) {
                const int rowbase = wy * 64 + ti * 32;
                const int n = wx * 64 + tj * 32 + r32;
#pragma unroll
                for (int r = 0; r < 16; ++r) {
                    const int m = rowbase + (r & 3) + 8 * (r >> 2) + 4 * khalf;
                    const float v = acc[ti][tj][r];
                    pout[m * NROW + n] = v;
                    if (m == n) diagP[b * NROW + m] = v;
                }
            }
    }

    cg::this_grid().sync();

    // ================= phase 2: reduce + log-softmax + KL =================
    if (b < NROW) {
        __shared__ float red[4];
        __shared__ float gii_s[2];
        __shared__ float Arow[2][NROW];

        const int i = b;
        const int s = t >> 7;          // 0 = image set, 1 = lang set
        const int j = t & 127;
        const int w = t >> 6;          // wave id 0..3
        const float et = expf(temp[0]);

        const int   base = s ? NC0 : 0;
        const int   nc   = s ? NC1 : NC0;
        const float* Ps  = partials + (size_t)base * PAIRS;
        const float* Ds  = diagP + base * NROW;

        // gij: 8 independent accumulators -> short dependency chains
        float a[8];
#pragma unroll
        for (int u = 0; u < 8; ++u) a[u] = 0.0f;
        {
            const float* p = Ps + i * NROW + j;
            for (int c = 0; c < nc; c += 8) {
#pragma unroll
                for (int u = 0; u < 8; ++u) a[u] += p[(size_t)(c + u) * PAIRS];
            }
        }
        const float gij = ((a[0] + a[1]) + (a[2] + a[3])) + ((a[4] + a[5]) + (a[6] + a[7]));

        // gjj (coalesced in j)
        float d[4];
#pragma unroll
        for (int u = 0; u < 4; ++u) d[u] = 0.0f;
        {
            const float* p = Ds + j;
            for (int c = 0; c < nc; c += 4) {
#pragma unroll
                for (int u = 0; u < 4; ++u) d[u] += p[(c + u) * NROW];
            }
        }
        const float gjj = (d[0] + d[1]) + (d[2] + d[3]);

        if (j == i) gii_s[s] = gjj;
        __syncthreads();
        const float gii = gii_s[s];

        // diagonal is exactly zero by construction in the reference
        const float sq   = (i == j) ? 0.0f : (gii + gjj - 2.0f * gij);
        const float dist = sq > 0.0f ? sqrtf(sq) : 0.0f;
        const float pre  = -dist * et;

        // per-half (128-thread) max
        float m = waveMax64(pre);
        if ((t & 63) == 0) red[w] = m;
        __syncthreads();
        m = fmaxf(red[2 * s], red[2 * s + 1]);
        __syncthreads();

        // per-half sum of exp
        float e = expf(pre - m);
        float sum = waveSum64(e);
        if ((t & 63) == 0) red[w] = sum;
        __syncthreads();
        sum = red[2 * s] + red[2 * s + 1];

        const float A = pre - (m + logf(sum));
        Arow[s][j] = A;
        __syncthreads();

        if (s == 0) {
            const float Af = Arow[0][j];
            const float Ag = Arow[1][j];
            atomicAdd(out + j, expf(Ag) * (Ag - Af));   // column sum over i
        }
    }
}

// ---------------------------------------------------------------------------
extern "C" void kernel_launch(void* const* d_in, const int* in_sizes, int n_in,
                              void* d_out, int out_size, void* d_ws, size_t ws_size,
                              hipStream_t stream)
{
    const float* img  = (const float*)d_in[0];
    const float* lng  = (const float*)d_in[1];
    const float* temp = (const float*)d_in[2];
    float* out = (float*)d_out;

    float* partials = (float*)d_ws;                       // 192*16384*4 = 12.6 MB
    float* diagP    = partials + (size_t)NCHUNK * PAIRS;  // 192*128*4   = 98 KB

    void* args[] = { (void*)&img, (void*)&lng, (void*)&partials,
                     (void*)&diagP, (void*)&temp, (void*)&out };
    hipLaunchCooperativeKernel((const void*)k_fused, dim3(NCHUNK), dim3(256),
                               args, 0, stream);
}

// Round 5
// 85.012 us; speedup vs baseline: 1.4728x; 1.4728x over previous
//
#include <hip/hip_runtime.h>
#include <hip/hip_bf16.h>
#include <math.h>

// Problem constants (from reference setup_inputs):
//   image_feats: (128, 64, 128) fp32 -> F0: 128 rows x 8192
//   lang_feats:  (128, 32, 128) fp32 -> F1: 128 rows x 4096
//   temperature: scalar fp32
// Output: (128,) fp32 = column sums over i of exp(A_g)*(A_g - A_f)
//
// Best-measured configuration (round-2 bench: 85.3 us total, where ~84.6 us
// is the harness's two 256 MiB 0xAA ws-poison fills at ~80% HBM peak).
// Two kernels, no cooperative sync (grid sync measured at ~49 us -- never).

#define NROW 128
#define PAIRS 16384          // 128*128
#define D0 8192
#define D1 4096
#define NC0 128              // D0 / 64
#define NC1 64               // D1 / 64
#define NCHUNK 192           // NC0 + NC1
#define ROWSTRIDE 140        // words per k-slice (swizzled 128-float row, max pos 139)

// Swizzle: pos(r) = r + 4*(r/32). Keeps 16B alignment (multiples of 4 stay
// multiples of 4), keeps any aligned 8-word fragment contiguous, and turns
// the 4-way bank conflict of b-fragment reads (8*tj vs 8*(tj+4) = +32 words)
// into a free 2-way: banks of swz(8*tj) = {0,8,16,24,4,12,20,28}*2.
__device__ __forceinline__ int swz(int r) { return r + ((r >> 5) << 2); }

// ---------------------------------------------------------------------------
// Kernel 1: split-K Gram partials. Block b = one 64-column K-chunk, covering
// ALL 128x128 pairs. 256 threads as 16x16, each owns an 8x8 register tile.
// LDS is k-major (transposed) so fragment reads are ds_read_b128.
// Also writes per-chunk diagonal partials, and block 0 zeroes d_out.
// ---------------------------------------------------------------------------
__global__ __launch_bounds__(256) void k_gram(
    const float* __restrict__ F0, const float* __restrict__ F1,
    float* __restrict__ partials, float* __restrict__ diagP,
    float* __restrict__ out)
{
    __shared__ float lds[64 * ROWSTRIDE];   // 35 KB

    const int b = blockIdx.x;
    const int t = threadIdx.x;
    if (b == 0 && t < NROW) out[t] = 0.0f;  // zero output for k_kl atomics

    const float* F; int D, chunk;
    if (b < NC0) { F = F0; D = D0; chunk = b; }
    else         { F = F1; D = D1; chunk = b - NC0; }
    const int k0 = chunk * 64;

    // ---- stage 128 rows x 64 cols, transposed + swizzled ----
    {
        const int rr = t >> 4;           // 0..15
        const int c4 = (t & 15) * 4;     // 0..60 step 4
#pragma unroll
        for (int it = 0; it < 8; ++it) {
            const int r = it * 16 + rr;
            const float4 v = *(const float4*)(F + (size_t)r * D + k0 + c4);
            const int p = swz(r);
            lds[(c4 + 0) * ROWSTRIDE + p] = v.x;
            lds[(c4 + 1) * ROWSTRIDE + p] = v.y;
            lds[(c4 + 2) * ROWSTRIDE + p] = v.z;
            lds[(c4 + 3) * ROWSTRIDE + p] = v.w;
        }
    }
    __syncthreads();

    const int ti = t >> 4, tj = t & 15;
    const int i0 = ti * 8, j0 = tj * 8;
    const int ia = swz(i0);              // 8-word fragment stays contiguous
    const int ib = swz(j0);

    float acc[8][8];
#pragma unroll
    for (int p = 0; p < 8; ++p)
#pragma unroll
        for (int q = 0; q < 8; ++q) acc[p][q] = 0.0f;

#pragma unroll 8
    for (int k = 0; k < 64; ++k) {
        const float* row = lds + k * ROWSTRIDE;
        const float4 a0 = *(const float4*)(row + ia);
        const float4 a1 = *(const float4*)(row + ia + 4);
        const float4 b0 = *(const float4*)(row + ib);
        const float4 b1 = *(const float4*)(row + ib + 4);
        const float a[8]  = {a0.x, a0.y, a0.z, a0.w, a1.x, a1.y, a1.z, a1.w};
        const float bb[8] = {b0.x, b0.y, b0.z, b0.w, b1.x, b1.y, b1.z, b1.w};
#pragma unroll
        for (int p = 0; p < 8; ++p)
#pragma unroll
            for (int q = 0; q < 8; ++q)
                acc[p][q] = fmaf(a[p], bb[q], acc[p][q]);
    }

    float* __restrict__ pout = partials + (size_t)b * PAIRS;
#pragma unroll
    for (int p = 0; p < 8; ++p) {
        float4* dst = (float4*)(pout + (i0 + p) * NROW + j0);
        dst[0] = make_float4(acc[p][0], acc[p][1], acc[p][2], acc[p][3]);
        dst[1] = make_float4(acc[p][4], acc[p][5], acc[p][6], acc[p][7]);
    }
    if (ti == tj) {                       // diagonal tile: stash diag partials
        float* dd = diagP + b * NROW + i0;
#pragma unroll
        for (int p = 0; p < 8; ++p) dd[p] = acc[p][p];
    }
}

// ---------------------------------------------------------------------------
// Kernel 2 (fused): split-K reduce for row i + diag, per-row log-softmax for
// both sets, KL, column-sum atomics. Block = row i, thread = column j.
// Diagonal exactness: gij (from partials) and gjj/gii (from diagP) are the
// same stored values summed in the same ascending-c order -> bitwise equal,
// so sq = gii + gjj - 2*gij == 0 exactly on the diagonal.
// ---------------------------------------------------------------------------
__device__ __forceinline__ float waveMax64(float v) {
#pragma unroll
    for (int off = 32; off > 0; off >>= 1) v = fmaxf(v, __shfl_xor(v, off, 64));
    return v;
}
__device__ __forceinline__ float waveSum64(float v) {
#pragma unroll
    for (int off = 32; off > 0; off >>= 1) v += __shfl_xor(v, off, 64);
    return v;
}
__device__ __forceinline__ float blockMax128(float v, float* red) {
    v = waveMax64(v);
    if ((threadIdx.x & 63) == 0) red[threadIdx.x >> 6] = v;
    __syncthreads();
    const float r = fmaxf(red[0], red[1]);
    __syncthreads();
    return r;
}
__device__ __forceinline__ float blockSum128(float v, float* red) {
    v = waveSum64(v);
    if ((threadIdx.x & 63) == 0) red[threadIdx.x >> 6] = v;
    __syncthreads();
    const float r = red[0] + red[1];
    __syncthreads();
    return r;
}

__global__ __launch_bounds__(128) void k_kl(
    const float* __restrict__ partials, const float* __restrict__ diagP,
    const float* __restrict__ temp, float* __restrict__ out)
{
    __shared__ float diag[NROW];
    __shared__ float red[2];
    const int i = blockIdx.x;
    const int j = threadIdx.x;
    const float et = expf(temp[0]);

    float A[2];
#pragma unroll
    for (int s = 0; s < 2; ++s) {
        const float* Ps = partials + (s ? (size_t)NC0 * PAIRS : 0);
        const float* Ds = diagP + (s ? NC0 * NROW : 0);
        const int nc = s ? NC1 : NC0;

        float gij = 0.0f, gjj = 0.0f;
        for (int c = 0; c < nc; ++c) {
            gij += Ps[c * PAIRS + i * NROW + j];
            gjj += Ds[c * NROW + j];
        }
        diag[j] = gjj;
        __syncthreads();
        const float gii = diag[i];
        __syncthreads();

        const float sq = gii + gjj - 2.0f * gij;    // exactly 0 when i==j
        const float dist = sq > 0.0f ? sqrtf(sq) : 0.0f;
        const float pre = -dist * et;
        const float m = blockMax128(pre, red);
        const float ssum = blockSum128(expf(pre - m), red);
        A[s] = pre - (m + logf(ssum));
    }
    const float kl = expf(A[1]) * (A[1] - A[0]);    // exp(Ag)*(Ag - Af)
    atomicAdd(out + j, kl);                          // column sum over i
}

// ---------------------------------------------------------------------------
extern "C" void kernel_launch(void* const* d_in, const int* in_sizes, int n_in,
                              void* d_out, int out_size, void* d_ws, size_t ws_size,
                              hipStream_t stream)
{
    const float* img  = (const float*)d_in[0];
    const float* lng  = (const float*)d_in[1];
    const float* temp = (const float*)d_in[2];
    float* out = (float*)d_out;

    float* partials = (float*)d_ws;                       // 192*16384 floats = 12.6 MB
    float* diagP    = partials + (size_t)NCHUNK * PAIRS;  // 192*128 floats

    k_gram<<<NCHUNK, 256, 0, stream>>>(img, lng, partials, diagP, out);
    k_kl<<<NROW, NROW, 0, stream>>>(partials, diagP, temp, out);
}